// Round 6
// baseline (185.259 us; speedup 1.0000x reference)
//
#include <hip/hip_runtime.h>
#include <math.h>

typedef unsigned short u16;
typedef short bf16x8 __attribute__((ext_vector_type(8)));   // 8 bf16 in 4 VGPR
typedef float f32x4 __attribute__((ext_vector_type(4)));
typedef u16 u16x4 __attribute__((ext_vector_type(4)));

#define RATIO 0.0625f   // 256^-0.5
#define EPSK 1e-4f
#define LOG2E 1.44269504f

__device__ __forceinline__ float bf2f(u16 u) {
  return __uint_as_float(((unsigned)u) << 16);
}
__device__ __forceinline__ u16 f2bf(float f) {
  unsigned x = __float_as_uint(f);
  x = x + 0x7fffu + ((x >> 16) & 1u);   // RNE
  return (u16)(x >> 16);
}
__device__ __forceinline__ unsigned cvtpk(float a, float b) {  // [lo=bf16(a), hi=bf16(b)]
  unsigned d;
  asm("v_cvt_pk_bf16_f32 %0, %1, %2" : "=v"(d) : "v"(a), "v"(b));
  return d;
}
__device__ __forceinline__ unsigned fenc(float f) {  // order-preserving float->uint
  unsigned u = __float_as_uint(f);
  return (u & 0x80000000u) ? ~u : (u | 0x80000000u);
}
__device__ __forceinline__ float fdec(unsigned e) {
  return (e & 0x80000000u) ? __uint_as_float(e & 0x7fffffffu) : __uint_as_float(~e);
}

using as1v = __attribute__((address_space(1))) void;
using as3v = __attribute__((address_space(3))) void;
__device__ __forceinline__ void gl_lds16(const void* g, void* l) {
  __builtin_amdgcn_global_load_lds((as1v*)g, (as3v*)l, 16, 0, 0);
}

// ---------------- all f32 -> bf16 conversions in one launch ----------------
__global__ __launch_bounds__(256) void cvt_all(
    const float* __restrict__ X, const float* __restrict__ Wq, const float* __restrict__ Wk,
    const float* __restrict__ Wv, const float* __restrict__ Wff, const float* __restrict__ proj,
    u16* __restrict__ Xbf, u16* __restrict__ Wqkv, u16* __restrict__ Wffb, u16* __restrict__ Pbf) {
  long bid = blockIdx.x;
  const float* src;
  u16* dst;
  long off;
  float sc = 1.f;
  if (bid < 8192) { src = X; dst = Xbf; off = bid; }
  else if (bid < 9216) { src = Wq; dst = Wqkv; off = bid - 8192; }
  else if (bid < 10240) { src = Wk; dst = Wqkv + 1048576; off = bid - 9216; }
  else if (bid < 11264) { src = Wv; dst = Wqkv + 2097152; off = bid - 10240; }
  else if (bid < 12288) { src = Wff; dst = Wffb; off = bid - 11264; }
  else { src = proj; dst = Pbf; off = bid - 12288; sc = 0.125f; }
  long i = (off * 256 + threadIdx.x) * 4;
  f32x4 v = *(const f32x4*)(src + i);
  u16x4 o;
#pragma unroll
  for (int j = 0; j < 4; ++j) o[j] = f2bf(v[j] * sc);
  *(u16x4*)(dst + i) = o;
}

// =====================================================================
// Ring GEMM v2: 256x128 tile, BK=32, 8 waves (4M x 2N), 64x64 per wave.
// Ring-of-3 LDS slots of 24 KB => 72 KB total => 2 blocks/CU (the
// second resident block provides the overlap a single barrier-locked
// block can't). ONE barrier + ONE counted vmcnt(3) per K-tile; staging
// runs 2 tiles ahead. 64B-row XOR swizzle: slot' = hi ^ ((row>>1)&3)
// (2 lanes/bank on reads = conflict-free); source pre-swizzled to
// match (gl_lds writes linearly). EPI 0 = qkv, EPI 1 = ff.
// =====================================================================
template <int EPI, int NB>
__global__ __launch_bounds__(512, 4) void gemmring(
    const u16* __restrict__ A, const u16* __restrict__ Bw,
    const float* __restrict__ bq, const float* __restrict__ bk,
    const float* __restrict__ bv, const float* __restrict__ mask,
    u16* __restrict__ Q, u16* __restrict__ Kb, u16* __restrict__ Vt,
    float* __restrict__ Of, const float* __restrict__ bff) {
  __shared__ __align__(16) u16 lds[3 * 12288];  // 72 KB: slot = [A 256x32 | B 128x32]
  const int nt = 32;  // K = 1024, BK = 32
  int tid = threadIdx.x;
  int l = tid & 63, w = tid >> 6;
  int wm = w >> 1, wn = w & 1;
  int lo = l & 15, hi = l >> 4;
  int bid = blockIdx.x;
  int swz = (bid & 7) * ((NB * 32) / 8) + (bid >> 3);  // bijective XCD swizzle (grid%8==0)
  long m0 = (long)(swz / NB) * 256;
  long c0 = (long)(swz % NB) * 128;
  int srow4 = l >> 2;                               // staging row-within-chunk 0..15
  int sce = ((l & 3) ^ ((l >> 3) & 3)) * 8;         // pre-swizzled source col (elems)
  f32x4 acc[4][4] = {};

  auto stage = [&](int t) {
    u16* ub = (u16*)lds + (t % 3) * 12288;
    long k0 = (long)t * 32;
    // A: 16 chunks of 16 rows x 32 cols (1KB); wave w stages chunks w, w+8
#pragma unroll
    for (int j = 0; j < 2; ++j) {
      int ch = w + j * 8;
      long row = m0 + ch * 16 + srow4;
      gl_lds16(A + row * 1024 + k0 + sce, ub + ch * 512);
    }
    // B: 8 chunks; wave w stages chunk w
    {
      long row = c0 + w * 16 + srow4;
      gl_lds16(Bw + row * 1024 + k0 + sce, ub + 8192 + w * 512);
    }
  };

  // prologue: tiles 0 and 1 in flight (6 loads/thread)
  stage(0);
  stage(1);

  int arb = (wm & 1) * 64;
  for (int t = 0; t < nt; ++t) {
    // wait tile t's 3 loads (leave tile t+1's 3 in flight)
    if (t < nt - 1) {
      asm volatile("s_waitcnt vmcnt(3)" ::: "memory");
    } else {
      asm volatile("s_waitcnt vmcnt(0)" ::: "memory");
    }
    __builtin_amdgcn_s_barrier();
    __builtin_amdgcn_sched_barrier(0);
    const u16* Au = (const u16*)lds + (t % 3) * 12288 + (wm >> 1) * 4096;
    const u16* Bu = (const u16*)lds + (t % 3) * 12288 + 8192;
    bf16x8 areg[4], breg[4];
#pragma unroll
    for (int mf = 0; mf < 4; ++mf) {
      int lr = arb + mf * 16 + lo;
      areg[mf] = *(const bf16x8*)(Au + lr * 32 + ((hi * 8) ^ (((lr >> 1) & 3) << 3)));
    }
#pragma unroll
    for (int nf = 0; nf < 4; ++nf) {
      int lr = wn * 64 + nf * 16 + lo;
      breg[nf] = *(const bf16x8*)(Bu + lr * 32 + ((hi * 8) ^ (((lr >> 1) & 3) << 3)));
    }
    // stage tile t+2 into slot (t+2)%3 == (t-1)%3 (its readers finished
    // before barrier(t) above)
    if (t + 2 < nt) stage(t + 2);
    // 16 MFMA; compiler interleaves with partial lgkmcnt waits
#pragma unroll
    for (int mf = 0; mf < 4; ++mf)
#pragma unroll
      for (int nf = 0; nf < 4; ++nf)
        acc[mf][nf] = __builtin_amdgcn_mfma_f32_16x16x32_bf16(areg[mf], breg[nf],
                                                              acc[mf][nf], 0, 0, 0);
  }

  // ---- epilogue ----
  long rowb = m0 + wm * 64;
  if (EPI == 0) {
    int wsel = (int)(c0 >> 10);  // 0=Q 1=K 2=V
    long cw = c0 & 1023;
    if (wsel < 2) {
      const float* bias = wsel ? bk : bq;
      u16* O = wsel ? Kb : Q;
#pragma unroll
      for (int mf = 0; mf < 4; ++mf)
#pragma unroll
        for (int nf = 0; nf < 4; ++nf) {
          long col = cw + wn * 64 + nf * 16 + lo;
          float bi = bias[col];
#pragma unroll
          for (int r = 0; r < 4; ++r) {
            long row = rowb + mf * 16 + hi * 4 + r;
            O[row * 1024 + col] = f2bf(acc[mf][nf][r] + bi);
          }
        }
    } else {
#pragma unroll
      for (int mf = 0; mf < 4; ++mf) {
        long t4 = rowb + mf * 16 + hi * 4;  // 4 consecutive tokens
        long b = t4 >> 12;
        long nn = t4 & 4095;
#pragma unroll
        for (int nf = 0; nf < 4; ++nf) {
          long col = cw + wn * 64 + nf * 16 + lo;
          float bi = bv[col];
          long h = col >> 6, e = col & 63;
          u16x4 pk;
#pragma unroll
          for (int r = 0; r < 4; ++r) pk[r] = f2bf((acc[mf][nf][r] + bi) * mask[t4 + r]);
          *(u16x4*)&Vt[((b * 16 + h) * 64 + e) * 4096 + nn] = pk;
        }
      }
    }
  } else {
#pragma unroll
    for (int mf = 0; mf < 4; ++mf)
#pragma unroll
      for (int nf = 0; nf < 4; ++nf) {
        long col = c0 + wn * 64 + nf * 16 + lo;
        float bi = bff[col];
#pragma unroll
        for (int r = 0; r < 4; ++r) {
          long row = rowb + mf * 16 + hi * 4 + r;
          Of[row * 1024 + col] = acc[mf][nf][r] + bi;
        }
      }
  }
}

// ---------------- key global max: mm = max over (n,r) of mask*dd ----------------
__global__ __launch_bounds__(256) void keymax_kernel(
    const u16* __restrict__ K, const u16* __restrict__ Pbf,
    const float* __restrict__ mask, unsigned* __restrict__ menc) {
  __shared__ u16 lP[256 * 64];  // 32KB
  __shared__ u16 lQ[64 * 64];   // 8KB
  __shared__ float smask[64];
  __shared__ float swmax[4];
  int tid = threadIdx.x, l = tid & 63, w = tid >> 6;
  int h = blockIdx.y;
  long t0 = (long)blockIdx.x * 64;
  int bh = (int)(t0 >> 12) * 16 + h;
#pragma unroll
  for (int i = 0; i < 8; ++i) {
    int ch = w * 8 + i;
    gl_lds16(Pbf + (long)(ch * 8 + (l >> 3)) * 64 + (l & 7) * 8, lP + ch * 512);
  }
#pragma unroll
  for (int i = 0; i < 2; ++i) {
    int ch = w * 2 + i;
    long tok = t0 + ch * 8 + (l >> 3);
    gl_lds16(K + tok * 1024 + (long)h * 64 + (l & 7) * 8, lQ + ch * 512);
  }
  if (tid < 64) smask[tid] = mask[t0 + tid];
  asm volatile("s_waitcnt vmcnt(0)" ::: "memory");
  __syncthreads();
  f32x4 acc[4][4] = {};
  int lo = l & 15, hi = l >> 4;
#pragma unroll
  for (int k2 = 0; k2 < 2; ++k2) {
    bf16x8 af[4], bb[4];
#pragma unroll
    for (int m = 0; m < 4; ++m)
      af[m] = *(const bf16x8*)(lQ + (m * 16 + lo) * 64 + k2 * 32 + hi * 8);
#pragma unroll
    for (int n = 0; n < 4; ++n)
      bb[n] = *(const bf16x8*)(lP + (w * 64 + n * 16 + lo) * 64 + k2 * 32 + hi * 8);
#pragma unroll
    for (int m = 0; m < 4; ++m)
#pragma unroll
      for (int n = 0; n < 4; ++n)
        acc[m][n] = __builtin_amdgcn_mfma_f32_16x16x32_bf16(af[m], bb[n], acc[m][n], 0, 0, 0);
  }
  float mm = -3.4e38f;
#pragma unroll
  for (int m = 0; m < 4; ++m)
#pragma unroll
    for (int r = 0; r < 4; ++r) {
      float mv = smask[m * 16 + hi * 4 + r];
#pragma unroll
      for (int n = 0; n < 4; ++n) mm = fmaxf(mm, mv * acc[m][n][r]);
    }
#pragma unroll
  for (int s = 1; s < 64; s <<= 1) mm = fmaxf(mm, __shfl_xor(mm, s, 64));
  if (l == 0) swmax[w] = mm;
  __syncthreads();
  if (tid == 0) {
    float bm = fmaxf(fmaxf(swmax[0], swmax[1]), fmaxf(swmax[2], swmax[3]));
    atomicMax(&menc[bh], fenc(bm));
  }
}

// =====================================================================
// kctx: per (bh, 512-token block = 2 chunks of 256): recompute kp in LDS,
// accumulate ctx[r][e] + ksum partials. 512 threads, 8 waves (32 r each).
// =====================================================================
__global__ __launch_bounds__(512) void kctx(
    const u16* __restrict__ Kg, const u16* __restrict__ Pbf,
    const u16* __restrict__ Vt, const float* __restrict__ mask,
    const unsigned* __restrict__ menc,
    float* __restrict__ part, float* __restrict__ part_ks) {
  __shared__ __align__(16) u16 projL[256 * 64];  // 32KB
  __shared__ __align__(16) u16 KL[256 * 64];     // 32KB
  __shared__ __align__(16) u16 VL[64 * 256];     // 32KB
  __shared__ __align__(16) u16 kpL[256 * 64];    // 32KB  [r][tok]
  __shared__ float sdiag[256];
  __shared__ float smask[256];
  int tid = threadIdx.x, l = tid & 63, wq = tid >> 6;
  int lo = l & 15, hi = l >> 4;
  int bh = blockIdx.x, ck2 = blockIdx.y;
  int b = bh >> 4, h = bh & 15;
  int rq = wq * 32;  // wave's 32 r-rows
  int rl = l >> 3;
  // stage proj once (4 chunks of 8 rows per wave)
#pragma unroll
  for (int i = 0; i < 4; ++i) {
    int c = i * 8 + wq;
    int row = c * 8 + rl;
    int sc_ = ((l & 7) * 8) ^ ((row & 7) << 3);
    gl_lds16(Pbf + (long)row * 64 + sc_, projL + c * 512);
  }
  float M = fdec(menc[bh]);
  bf16x8 ones;
#pragma unroll
  for (int e = 0; e < 8; ++e) ones[e] = (short)0x3F80;
  f32x4 acc2[2][4] = {};
  f32x4 acc_ks[2] = {};
  for (int s = 0; s < 2; ++s) {
    int ck = ck2 * 2 + s;
    long tg0 = (long)b * 4096 + (long)ck * 256;
    if (s) __syncthreads();  // all reads of previous chunk's KL/VL/sdiag done
    // stage K chunk [256][64]
#pragma unroll
    for (int i = 0; i < 4; ++i) {
      int c = i * 8 + wq;
      int row = c * 8 + rl;
      int sc_ = ((l & 7) * 8) ^ ((row & 7) << 3);
      gl_lds16(Kg + (tg0 + row) * 1024 + (long)h * 64 + sc_, KL + c * 512);
    }
    // stage Vt tile [64 e][256 n]
#pragma unroll
    for (int i = 0; i < 4; ++i) {
      int c = i * 8 + wq;
      int e = 2 * c + (l >> 5);
      int sc_ = ((l & 31) * 8) ^ ((e & 7) << 3);
      gl_lds16(Vt + ((long)bh * 64 + e) * 4096 + (long)ck * 256 + sc_, VL + c * 512);
    }
    asm volatile("s_waitcnt vmcnt(0)" ::: "memory");
    __syncthreads();
    // per-token diag + mask (threads 0-255)
    if (tid < 256) {
      float sm = 0.f;
#pragma unroll
      for (int j = 0; j < 8; ++j) {
        bf16x8 v = *(const bf16x8*)(KL + tid * 64 + ((j * 8) ^ ((tid & 7) << 3)));
#pragma unroll
        for (int e = 0; e < 8; ++e) {
          float f = bf2f((u16)v[e]);
          sm += f * f;
        }
      }
      sdiag[tid] = sm * (1.f / 128.f);
      smask[tid] = mask[tg0 + tid];
    }
    __syncthreads();
    for (int sc = 0; sc < 4; ++sc) {
      // dd: D[tok][r], A = K rows (sc*64..), B = proj rows (rq..rq+31)
      f32x4 accT[4][2] = {};
#pragma unroll
      for (int kk = 0; kk < 2; ++kk) {
        bf16x8 aK[4], bP[2];
#pragma unroll
        for (int m = 0; m < 4; ++m)
          aK[m] = *(const bf16x8*)(KL + (sc * 64 + m * 16 + lo) * 64 +
                                   ((kk * 32 + hi * 8) ^ ((lo & 7) << 3)));
#pragma unroll
        for (int nf = 0; nf < 2; ++nf)
          bP[nf] = *(const bf16x8*)(projL + (rq + nf * 16 + lo) * 64 +
                                    ((kk * 32 + hi * 8) ^ ((lo & 7) << 3)));
#pragma unroll
        for (int m = 0; m < 4; ++m)
#pragma unroll
          for (int nf = 0; nf < 2; ++nf)
            accT[m][nf] = __builtin_amdgcn_mfma_f32_16x16x32_bf16(aK[m], bP[nf], accT[m][nf], 0, 0, 0);
      }
      // kp epilogue -> kpL[r][tok] (own rows rq..rq+31)
#pragma unroll
      for (int m = 0; m < 4; ++m) {
        int tb = m * 16 + hi * 4;
        float mv[4], dg[4];
#pragma unroll
        for (int r = 0; r < 4; ++r) {
          int tk = sc * 64 + tb + r;
          mv[r] = smask[tk];
          dg[r] = sdiag[tk];
        }
#pragma unroll
        for (int nf = 0; nf < 2; ++nf) {
          int rr = rq + nf * 16 + lo;
          float v[4];
#pragma unroll
          for (int r = 0; r < 4; ++r) {
            float x = mv[r] * accT[m][nf][r] - mv[r] * mv[r] * dg[r] - M;
            v[r] = RATIO * (__builtin_exp2f(x * LOG2E) + EPSK);
          }
          uint2 pk;
          pk.x = cvtpk(v[0], v[1]);
          pk.y = cvtpk(v[2], v[3]);
          *(uint2*)(kpL + rr * 64 + (tb ^ ((lo & 7) << 3))) = pk;
        }
      }
      // ctx MFMA: D[r][e] += kp[r][n] * Vt[e][n]; + ksum via ones
#pragma unroll
      for (int kk = 0; kk < 2; ++kk) {
        bf16x8 aC[2], bV[4];
#pragma unroll
        for (int m = 0; m < 2; ++m)
          aC[m] = *(const bf16x8*)(kpL + (rq + m * 16 + lo) * 64 +
                                   ((kk * 32 + hi * 8) ^ ((lo & 7) << 3)));
#pragma unroll
        for (int nf = 0; nf < 4; ++nf)
          bV[nf] = *(const bf16x8*)(VL + (nf * 16 + lo) * 256 +
                                    ((sc * 64 + kk * 32 + hi * 8) ^ ((lo & 7) << 3)));
#pragma unroll
        for (int m = 0; m < 2; ++m) {
          acc_ks[m] = __builtin_amdgcn_mfma_f32_16x16x32_bf16(aC[m], ones, acc_ks[m], 0, 0, 0);
#pragma unroll
          for (int nf = 0; nf < 4; ++nf)
            acc2[m][nf] = __builtin_amdgcn_mfma_f32_16x16x32_bf16(aC[m], bV[nf], acc2[m][nf], 0, 0, 0);
        }
      }
    }
  }
  // write partials: part[(bh*8+ck2)*64 + e][r] f32
  long pb = ((long)bh * 8 + ck2) * 64;
#pragma unroll
  for (int m = 0; m < 2; ++m) {
    int r0 = rq + m * 16 + hi * 4;
#pragma unroll
    for (int nf = 0; nf < 4; ++nf) {
      int e = nf * 16 + lo;
      *(f32x4*)&part[(pb + e) * 256 + r0] = acc2[m][nf];
    }
    if (lo == 0)
      *(f32x4*)&part_ks[((long)bh * 8 + ck2) * 256 + r0] = acc_ks[m];
  }
}

// ---------------- reduce partials -> ctxb [bh][80][256] bf16 ----------------
__global__ __launch_bounds__(256) void ctx_reduce2(const float* __restrict__ part,
                                                   const float* __restrict__ part_ks,
                                                   u16* __restrict__ ctxb) {
  int bid = blockIdx.x;
  int bh = bid / 80, j = bid % 80;
  int r = threadIdx.x;
  float s = 0.f;
  if (j < 64) {
#pragma unroll
    for (int c = 0; c < 8; ++c) s += part[(((long)bh * 8 + c) * 64 + j) * 256 + r];
  } else if (j == 64) {
#pragma unroll
    for (int c = 0; c < 8; ++c) s += part_ks[((long)bh * 8 + c) * 256 + r];
  }
  ctxb[((long)bh * 80 + j) * 256 + r] = f2bf(s);
}

// =====================================================================
// qattn: per (bh, 128-token block): recompute qp in LDS (dd transposed,
// cross-wave rowmax), then D2[j][tok] = ctxb[j][r]*qp[tok][r]; j=64 row
// is the denominator (in-lane).
// =====================================================================
__global__ __launch_bounds__(256) void qattn(
    const u16* __restrict__ Qg, const u16* __restrict__ Pbf,
    const u16* __restrict__ ctxbg, u16* __restrict__ attn) {
  __shared__ __align__(16) u16 L[69632];  // proj 16384 | ctxb 20480 | Q/qp 32768
  __shared__ float sdiagq[128];
  __shared__ float sredq[4 * 128];
  u16* projL = L;
  u16* CL = L + 16384;
  u16* QL = L + 36864;   // overlaid by qp after the rowmax barrier
  u16* qpL = L + 36864;  // [128 tok][256 r]
  int tid = threadIdx.x, l = tid & 63, wq = tid >> 6;
  int lo = l & 15, hi = l >> 4;
  int bh = blockIdx.x;
  int b = bh >> 4, h = bh & 15;
  long tokb = (long)b * 4096 + (long)blockIdx.y * 128;
  int rq = wq * 64, tq = wq * 32;
  // stage proj (swizzled)
#pragma unroll
  for (int i = 0; i < 8; ++i) {
    int c = wq * 8 + i;
    int row = c * 8 + (l >> 3);
    int sc_ = ((l & 7) * 8) ^ ((row & 7) << 3);
    gl_lds16(Pbf + (long)row * 64 + sc_, projL + c * 512);
  }
  // stage Q tile [128][64] (swizzled)
#pragma unroll
  for (int i = 0; i < 4; ++i) {
    int c = wq * 4 + i;
    int row = c * 8 + (l >> 3);
    int sc_ = ((l & 7) * 8) ^ ((row & 7) << 3);
    gl_lds16(Qg + (tokb + row) * 1024 + (long)h * 64 + sc_, QL + c * 512);
  }
  // stage ctxb tile [80][256] (swizzled)
#pragma unroll
  for (int i = 0; i < 10; ++i) {
    int c = wq * 10 + i;
    int j = 2 * c + (l >> 5);
    int sc_ = ((l & 31) * 8) ^ ((j & 7) << 3);
    gl_lds16(ctxbg + ((long)bh * 80 + j) * 256 + sc_, CL + c * 512);
  }
  asm volatile("s_waitcnt vmcnt(0)" ::: "memory");
  __syncthreads();
  // diag per token (threads 0-127)
  if (tid < 128) {
    float s = 0.f;
#pragma unroll
    for (int j = 0; j < 8; ++j) {
      bf16x8 v = *(const bf16x8*)(QL + tid * 64 + ((j * 8) ^ ((tid & 7) << 3)));
#pragma unroll
      for (int e = 0; e < 8; ++e) {
        float f = bf2f((u16)v[e]);
        s += f * f;
      }
    }
    sdiagq[tid] = s * (1.f / 128.f);
  }
  // dd transposed: D[r][tok], A = proj rows r (wave quadrant), B = Q rows tok
  f32x4 acc[4][8];
#pragma unroll
  for (int m = 0; m < 4; ++m)
#pragma unroll
    for (int nf = 0; nf < 8; ++nf) acc[m][nf] = f32x4{0.f, 0.f, 0.f, 0.f};
#pragma unroll
  for (int kk = 0; kk < 2; ++kk) {
    bf16x8 aP[4], bQ[8];
#pragma unroll
    for (int m = 0; m < 4; ++m)
      aP[m] = *(const bf16x8*)(projL + (rq + m * 16 + lo) * 64 +
                               ((kk * 32 + hi * 8) ^ ((lo & 7) << 3)));
#pragma unroll
    for (int nf = 0; nf < 8; ++nf)
      bQ[nf] = *(const bf16x8*)(QL + (nf * 16 + lo) * 64 +
                                ((kk * 32 + hi * 8) ^ ((lo & 7) << 3)));
#pragma unroll
    for (int m = 0; m < 4; ++m)
#pragma unroll
      for (int nf = 0; nf < 8; ++nf)
        acc[m][nf] = __builtin_amdgcn_mfma_f32_16x16x32_bf16(aP[m], bQ[nf], acc[m][nf], 0, 0, 0);
  }
  // wave-local rowmax per token
#pragma unroll
  for (int nf = 0; nf < 8; ++nf) {
    float vm = acc[0][nf][0];
#pragma unroll
    for (int m = 0; m < 4; ++m)
#pragma unroll
      for (int r = 0; r < 4; ++r) vm = fmaxf(vm, acc[m][nf][r]);
    vm = fmaxf(vm, __shfl_xor(vm, 16, 64));
    vm = fmaxf(vm, __shfl_xor(vm, 32, 64));
    if (hi == 0) sredq[wq * 128 + nf * 16 + lo] = vm;
  }
  __syncthreads();  // also separates QL reads from qp writes
  // final rowmax + epilogue -> qpL[tok][r]
#pragma unroll
  for (int nf = 0; nf < 8; ++nf) {
    int tk = nf * 16 + lo;
    float rm = fmaxf(fmaxf(sredq[tk], sredq[128 + tk]),
                     fmaxf(sredq[256 + tk], sredq[384 + tk]));
    float dg = sdiagq[tk];
#pragma unroll
    for (int m = 0; m < 4; ++m) {
      int r0 = rq + m * 16 + hi * 4;
      float v[4];
#pragma unroll
      for (int r = 0; r < 4; ++r) {
        float x = acc[m][nf][r] - dg - rm;
        v[r] = RATIO * (__builtin_exp2f(x * LOG2E) + EPSK);
      }
      uint2 pk;
      pk.x = cvtpk(v[0], v[1]);
      pk.y = cvtpk(v[2], v[3]);
      *(uint2*)(qpL + tk * 256 + (r0 ^ ((lo & 7) << 3))) = pk;
    }
  }
  __syncthreads();
  // D2[j][tok] = sum_r ctxb[j][r] * qp[tok][r]; wave owns 32 tok
  f32x4 acc2[5][2];
#pragma unroll
  for (int m = 0; m < 5; ++m)
#pragma unroll
    for (int n = 0; n < 2; ++n) acc2[m][n] = f32x4{0.f, 0.f, 0.f, 0.f};
#pragma unroll
  for (int ks = 0; ks < 8; ++ks) {
    bf16x8 aC[5], bQp[2];
#pragma unroll
    for (int m = 0; m < 5; ++m)
      aC[m] = *(const bf16x8*)(CL + (m * 16 + lo) * 256 +
                               ((ks * 32 + hi * 8) ^ ((lo & 7) << 3)));
#pragma unroll
    for (int n = 0; n < 2; ++n)
      bQp[n] = *(const bf16x8*)(qpL + (tq + n * 16 + lo) * 256 +
                                ((ks * 32 + hi * 8) ^ ((lo & 7) << 3)));
#pragma unroll
    for (int m = 0; m < 5; ++m)
#pragma unroll
      for (int n = 0; n < 2; ++n)
        acc2[m][n] = __builtin_amdgcn_mfma_f32_16x16x32_bf16(aC[m], bQp[n], acc2[m][n], 0, 0, 0);
  }
  // epilogue: denom at j=64 (m=4, hi=0, reg=0) -> broadcast via shfl(lane = lo)
#pragma unroll
  for (int n = 0; n < 2; ++n) {
    float dv = __shfl(acc2[4][n][0], lo, 64);
    float di = 1.f / dv;
    long tok = tokb + tq + n * 16 + lo;
#pragma unroll
    for (int m = 0; m < 4; ++m) {
      int j0 = m * 16 + hi * 4;
      uint2 pk;
      pk.x = cvtpk(acc2[m][n][0] * di, acc2[m][n][1] * di);
      pk.y = cvtpk(acc2[m][n][2] * di, acc2[m][n][3] * di);
      *(uint2*)&attn[tok * 1024 + (long)h * 64 + j0] = pk;
    }
  }
}

extern "C" void kernel_launch(void* const* d_in, const int* in_sizes, int n_in,
                              void* d_out, int out_size, void* d_ws, size_t ws_size,
                              hipStream_t stream) {
  const float* X = (const float*)d_in[0];
  const float* mask = (const float*)d_in[1];
  const float* Wq = (const float*)d_in[2];
  const float* bq = (const float*)d_in[3];
  const float* Wk = (const float*)d_in[4];
  const float* bk = (const float*)d_in[5];
  const float* Wv = (const float*)d_in[6];
  const float* bv = (const float*)d_in[7];
  const float* Wff = (const float*)d_in[8];
  const float* bff = (const float*)d_in[9];
  const float* proj = (const float*)d_in[10];
  float* out = (float*)d_out;

  char* p = (char*)d_ws;
  u16* Xbf = (u16*)p;   p += 16777216;   // [8192][1024] bf16; reused as attn
  u16* Wqkv = (u16*)p;  p += 6291456;    // [3072][1024]
  u16* Wffb = (u16*)p;  p += 2097152;    // [1024][1024]
  u16* Pbf = (u16*)p;   p += 32768;      // bf16(proj/8) [256][64]
  u16* Qbf = (u16*)p;   p += 16777216;
  u16* Kbf = (u16*)p;   p += 16777216;
  u16* Vt = (u16*)p;    p += 16777216;   // [bh*64+e][4096] (mask applied)
  u16* ctxb = (u16*)p;  p += 1310720;    // [bh][80][256]
  unsigned* menc = (unsigned*)p; p += 256;
  float* part = (float*)p;    p += 16777216;  // [bh*8][64][256] f32
  float* part_ks = (float*)p; p += 262144;    // [bh*8][256] f32
  u16* attn = Xbf;

  hipMemsetAsync(menc, 0, 128, stream);
  cvt_all<<<12304, 256, 0, stream>>>(X, Wq, Wk, Wv, Wff, proj, Xbf, Wqkv, Wffb, Pbf);
  gemmring<0, 24><<<768, 512, 0, stream>>>(Xbf, Wqkv, bq, bk, bv, mask, Qbf, Kbf, Vt, nullptr, nullptr);
  keymax_kernel<<<dim3(128, 16), 256, 0, stream>>>(Kbf, Pbf, mask, menc);
  kctx<<<dim3(32, 8), 512, 0, stream>>>(Kbf, Pbf, Vt, mask, menc, part, part_ks);
  ctx_reduce2<<<2560, 256, 0, stream>>>(part, part_ks, ctxb);
  qattn<<<dim3(32, 32), 256, 0, stream>>>(Qbf, Pbf, ctxb, attn);
  gemmring<1, 8><<<256, 512, 0, stream>>>(attn, Wffb, nullptr, nullptr, nullptr, nullptr,
                                          nullptr, nullptr, nullptr, out, bff);
}

// Round 7
// 162.307 us; speedup vs baseline: 1.1414x; 1.1414x over previous
//
#include <hip/hip_runtime.h>
#include <math.h>

typedef unsigned short u16;
typedef short bf16x8 __attribute__((ext_vector_type(8)));   // 8 bf16 in 4 VGPR
typedef float f32x4 __attribute__((ext_vector_type(4)));
typedef u16 u16x4 __attribute__((ext_vector_type(4)));

#define RATIO 0.0625f   // 256^-0.5
#define EPSK 1e-4f
#define LOG2E 1.44269504f

__device__ __forceinline__ float bf2f(u16 u) {
  return __uint_as_float(((unsigned)u) << 16);
}
__device__ __forceinline__ u16 f2bf(float f) {
  unsigned x = __float_as_uint(f);
  x = x + 0x7fffu + ((x >> 16) & 1u);   // RNE
  return (u16)(x >> 16);
}
__device__ __forceinline__ unsigned cvtpk(float a, float b) {  // [lo=bf16(a), hi=bf16(b)]
  unsigned d;
  asm("v_cvt_pk_bf16_f32 %0, %1, %2" : "=v"(d) : "v"(a), "v"(b));
  return d;
}

using as1v = __attribute__((address_space(1))) void;
using as3v = __attribute__((address_space(3))) void;
__device__ __forceinline__ void gl_lds16(const void* g, void* l) {
  __builtin_amdgcn_global_load_lds((as1v*)g, (as3v*)l, 16, 0, 0);
}

// ---------------- all f32 -> bf16 conversions in one launch ----------------
__global__ __launch_bounds__(256) void cvt_all(
    const float* __restrict__ X, const float* __restrict__ Wq, const float* __restrict__ Wk,
    const float* __restrict__ Wv, const float* __restrict__ Wff, const float* __restrict__ proj,
    u16* __restrict__ Xbf, u16* __restrict__ Wqkv, u16* __restrict__ Wffb, u16* __restrict__ Pbf) {
  long bid = blockIdx.x;
  const float* src;
  u16* dst;
  long off;
  float sc = 1.f;
  if (bid < 8192) { src = X; dst = Xbf; off = bid; }
  else if (bid < 9216) { src = Wq; dst = Wqkv; off = bid - 8192; }
  else if (bid < 10240) { src = Wk; dst = Wqkv + 1048576; off = bid - 9216; }
  else if (bid < 11264) { src = Wv; dst = Wqkv + 2097152; off = bid - 10240; }
  else if (bid < 12288) { src = Wff; dst = Wffb; off = bid - 11264; }
  else { src = proj; dst = Pbf; off = bid - 12288; sc = 0.125f; }
  long i = (off * 256 + threadIdx.x) * 4;
  f32x4 v = *(const f32x4*)(src + i);
  u16x4 o;
#pragma unroll
  for (int j = 0; j < 4; ++j) o[j] = f2bf(v[j] * sc);
  *(u16x4*)(dst + i) = o;
}

// =====================================================================
// Ring GEMM (R5-proven): 256x128 tile, BK=64, 8 waves (4M x 2N), 64x64
// per wave. Ring-of-3 LDS slots (144 KB). ONE barrier + ONE counted
// vmcnt(6) per K-tile; staging runs 2 tiles ahead. Read-side XOR swizzle
// with pre-swizzled global source (0 bank conflicts). EPI 0=qkv, 1=ff.
// =====================================================================
template <int EPI, int NB>
__global__ __launch_bounds__(512, 1) void gemmring(
    const u16* __restrict__ A, const u16* __restrict__ Bw,
    const float* __restrict__ bq, const float* __restrict__ bk,
    const float* __restrict__ bv, const float* __restrict__ mask,
    u16* __restrict__ Q, u16* __restrict__ Kb, u16* __restrict__ Vt,
    float* __restrict__ Of, const float* __restrict__ bff) {
  __shared__ __align__(16) u16 lds[3 * 24576];  // 144 KB: slot = [A 256x64 | B 128x64]
  const int nt = 16;  // K = 1024, BK = 64
  int tid = threadIdx.x;
  int l = tid & 63, w = tid >> 6;
  int wm = w >> 1, wn = w & 1;
  int lo = l & 15, hi = l >> 4;
  int bid = blockIdx.x;
  int swz = (bid & 7) * ((NB * 32) / 8) + (bid >> 3);  // bijective XCD swizzle (grid%8==0)
  long m0 = (long)(swz / NB) * 256;
  long c0 = (long)(swz % NB) * 128;
  int srow = tid >> 3;                              // staging row 0..63
  int sce = ((tid & 7) ^ ((tid >> 3) & 7)) * 8;     // pre-swizzled source col
  f32x4 acc[4][4] = {};

  auto stageA = [&](int t) {
    u16* ub = (u16*)lds + (t % 3) * 24576;
    long k0 = (long)t * 64;
#pragma unroll
    for (int u = 0; u < 2; ++u)
#pragma unroll
      for (int j = 0; j < 2; ++j) {
        long row = m0 + u * 128 + j * 64 + srow;
        gl_lds16(A + row * 1024 + k0 + sce, ub + u * 8192 + j * 4096 + tid * 8);
      }
  };
  auto stageB = [&](int t) {
    u16* ub = (u16*)lds + (t % 3) * 24576 + 16384;
    long k0 = (long)t * 64;
#pragma unroll
    for (int j = 0; j < 2; ++j) {
      long row = c0 + j * 64 + srow;
      gl_lds16(Bw + row * 1024 + k0 + sce, ub + j * 4096 + tid * 8);
    }
  };

  // prologue: tiles 0 and 1 in flight (12 loads/thread)
  stageA(0); stageB(0);
  stageA(1); stageB(1);

  int arb = (wm & 1) * 64;
  for (int t = 0; t < nt; ++t) {
    // wait tile t's 6 loads (leave tile t+1's 6 in flight)
    if (t < nt - 1) {
      asm volatile("s_waitcnt vmcnt(6)" ::: "memory");
    } else {
      asm volatile("s_waitcnt vmcnt(0)" ::: "memory");
    }
    __builtin_amdgcn_s_barrier();
    __builtin_amdgcn_sched_barrier(0);
    const u16* Au = (const u16*)lds + (t % 3) * 24576 + (wm >> 1) * 8192;
    const u16* Bu = (const u16*)lds + (t % 3) * 24576 + 16384;
    bf16x8 areg[4][2], breg[4][2];
#pragma unroll
    for (int mf = 0; mf < 4; ++mf) {
      int lrow = arb + mf * 16 + lo;
#pragma unroll
      for (int kk = 0; kk < 2; ++kk)
        areg[mf][kk] = *(const bf16x8*)(Au + lrow * 64 + ((kk * 32 + hi * 8) ^ ((lo & 7) << 3)));
    }
#pragma unroll
    for (int nf = 0; nf < 4; ++nf) {
      int lrow = wn * 64 + nf * 16 + lo;
#pragma unroll
      for (int kk = 0; kk < 2; ++kk)
        breg[nf][kk] = *(const bf16x8*)(Bu + lrow * 64 + ((kk * 32 + hi * 8) ^ ((lo & 7) << 3)));
    }
    // stage tile t+2 into slot (t+2)%3 == (t-1)%3 (its readers finished
    // before barrier(t) above)
    if (t + 2 < nt) { stageA(t + 2); stageB(t + 2); }
    // MFMA; compiler interleaves with partial lgkmcnt waits
#pragma unroll
    for (int mf = 0; mf < 4; ++mf)
#pragma unroll
      for (int nf = 0; nf < 4; ++nf)
#pragma unroll
        for (int kk = 0; kk < 2; ++kk)
          acc[mf][nf] = __builtin_amdgcn_mfma_f32_16x16x32_bf16(areg[mf][kk], breg[nf][kk],
                                                                acc[mf][nf], 0, 0, 0);
  }

  // ---- epilogue ----
  long rowb = m0 + wm * 64;
  if (EPI == 0) {
    int wsel = (int)(c0 >> 10);  // 0=Q 1=K 2=V
    long cw = c0 & 1023;
    if (wsel < 2) {
      const float* bias = wsel ? bk : bq;
      u16* O = wsel ? Kb : Q;
#pragma unroll
      for (int mf = 0; mf < 4; ++mf)
#pragma unroll
        for (int nf = 0; nf < 4; ++nf) {
          long col = cw + wn * 64 + nf * 16 + lo;
          float bi = bias[col];
#pragma unroll
          for (int r = 0; r < 4; ++r) {
            long row = rowb + mf * 16 + hi * 4 + r;
            O[row * 1024 + col] = f2bf(acc[mf][nf][r] + bi);
          }
        }
    } else {
#pragma unroll
      for (int mf = 0; mf < 4; ++mf) {
        long t4 = rowb + mf * 16 + hi * 4;  // 4 consecutive tokens
        long b = t4 >> 12;
        long nn = t4 & 4095;
#pragma unroll
        for (int nf = 0; nf < 4; ++nf) {
          long col = cw + wn * 64 + nf * 16 + lo;
          float bi = bv[col];
          long h = col >> 6, e = col & 63;
          u16x4 pk;
#pragma unroll
          for (int r = 0; r < 4; ++r) pk[r] = f2bf((acc[mf][nf][r] + bi) * mask[t4 + r]);
          *(u16x4*)&Vt[((b * 16 + h) * 64 + e) * 4096 + nn] = pk;
        }
      }
    }
  } else {
#pragma unroll
    for (int mf = 0; mf < 4; ++mf)
#pragma unroll
      for (int nf = 0; nf < 4; ++nf) {
        long col = c0 + wn * 64 + nf * 16 + lo;
        float bi = bff[col];
#pragma unroll
        for (int r = 0; r < 4; ++r) {
          long row = rowb + mf * 16 + hi * 4 + r;
          Of[row * 1024 + col] = acc[mf][nf][r] + bi;
        }
      }
  }
}

// =====================================================================
// kctx (online-max): per (bh, 512-token block = 2 chunks of 256):
// recompute kp-tilde = exp(mask*dd - mask^2*diag - Mw) in LDS with a
// per-wave RUNNING max Mw over mask*dd (rescaling accumulators by
// exp(Mw_old - Mw_new)); accumulate ctx/ksum partials; store Mw.
// Global key-max is reconstructed exactly in ctx_reduce2. No keymax
// pass, no atomics. RATIO and +EPSK applied in the reduce.
// =====================================================================
__global__ __launch_bounds__(512) void kctx(
    const u16* __restrict__ Kg, const u16* __restrict__ Pbf,
    const u16* __restrict__ Vt, const float* __restrict__ mask,
    float* __restrict__ part, float* __restrict__ part_ks,
    float* __restrict__ part_m) {
  __shared__ __align__(16) u16 projL[256 * 64];  // 32KB
  __shared__ __align__(16) u16 KL[256 * 64];     // 32KB
  __shared__ __align__(16) u16 VL[64 * 256];     // 32KB
  __shared__ __align__(16) u16 kpL[256 * 64];    // 32KB  [r][tok]
  __shared__ float sdiag[256];
  __shared__ float smask[256];
  int tid = threadIdx.x, l = tid & 63, wq = tid >> 6;
  int lo = l & 15, hi = l >> 4;
  int bh = blockIdx.x, ck2 = blockIdx.y;
  int b = bh >> 4, h = bh & 15;
  int rq = wq * 32;  // wave's 32 r-rows
  int rl = l >> 3;
  // stage proj once (4 chunks of 8 rows per wave)
#pragma unroll
  for (int i = 0; i < 4; ++i) {
    int c = i * 8 + wq;
    int row = c * 8 + rl;
    int sc_ = ((l & 7) * 8) ^ ((row & 7) << 3);
    gl_lds16(Pbf + (long)row * 64 + sc_, projL + c * 512);
  }
  bf16x8 ones;
#pragma unroll
  for (int e = 0; e < 8; ++e) ones[e] = (short)0x3F80;
  float Mw = -3.4e38f;
  f32x4 acc2[2][4] = {};
  f32x4 acc_ks[2] = {};
  for (int s = 0; s < 2; ++s) {
    int ck = ck2 * 2 + s;
    long tg0 = (long)b * 4096 + (long)ck * 256;
    if (s) __syncthreads();  // all reads of previous chunk's KL/VL/sdiag done
    // stage K chunk [256][64]
#pragma unroll
    for (int i = 0; i < 4; ++i) {
      int c = i * 8 + wq;
      int row = c * 8 + rl;
      int sc_ = ((l & 7) * 8) ^ ((row & 7) << 3);
      gl_lds16(Kg + (tg0 + row) * 1024 + (long)h * 64 + sc_, KL + c * 512);
    }
    // stage Vt tile [64 e][256 n]
#pragma unroll
    for (int i = 0; i < 4; ++i) {
      int c = i * 8 + wq;
      int e = 2 * c + (l >> 5);
      int sc_ = ((l & 31) * 8) ^ ((e & 7) << 3);
      gl_lds16(Vt + ((long)bh * 64 + e) * 4096 + (long)ck * 256 + sc_, VL + c * 512);
    }
    asm volatile("s_waitcnt vmcnt(0)" ::: "memory");
    __syncthreads();
    // per-token diag + mask (threads 0-255)
    if (tid < 256) {
      float sm = 0.f;
#pragma unroll
      for (int j = 0; j < 8; ++j) {
        bf16x8 v = *(const bf16x8*)(KL + tid * 64 + ((j * 8) ^ ((tid & 7) << 3)));
#pragma unroll
        for (int e = 0; e < 8; ++e) {
          float f = bf2f((u16)v[e]);
          sm += f * f;
        }
      }
      sdiag[tid] = sm * (1.f / 128.f);
      smask[tid] = mask[tg0 + tid];
    }
    __syncthreads();
    for (int sc = 0; sc < 4; ++sc) {
      // dd: D[tok][r], A = K rows (sc*64..), B = proj rows (rq..rq+31)
      f32x4 accT[4][2] = {};
#pragma unroll
      for (int kk = 0; kk < 2; ++kk) {
        bf16x8 aK[4], bP[2];
#pragma unroll
        for (int m = 0; m < 4; ++m)
          aK[m] = *(const bf16x8*)(KL + (sc * 64 + m * 16 + lo) * 64 +
                                   ((kk * 32 + hi * 8) ^ ((lo & 7) << 3)));
#pragma unroll
        for (int nf = 0; nf < 2; ++nf)
          bP[nf] = *(const bf16x8*)(projL + (rq + nf * 16 + lo) * 64 +
                                    ((kk * 32 + hi * 8) ^ ((lo & 7) << 3)));
#pragma unroll
        for (int m = 0; m < 4; ++m)
#pragma unroll
          for (int nf = 0; nf < 2; ++nf)
            accT[m][nf] = __builtin_amdgcn_mfma_f32_16x16x32_bf16(aK[m], bP[nf], accT[m][nf], 0, 0, 0);
      }
      // online max over mask*dd (wave-wide), rescale accumulators
      float mloc = -3.4e38f;
#pragma unroll
      for (int m = 0; m < 4; ++m) {
        int tb = m * 16 + hi * 4;
#pragma unroll
        for (int r = 0; r < 4; ++r) {
          float mv = smask[sc * 64 + tb + r];
#pragma unroll
          for (int nf = 0; nf < 2; ++nf) mloc = fmaxf(mloc, mv * accT[m][nf][r]);
        }
      }
#pragma unroll
      for (int sft = 1; sft < 64; sft <<= 1) mloc = fmaxf(mloc, __shfl_xor(mloc, sft, 64));
      float nM = fmaxf(Mw, mloc);
      float rs = __builtin_exp2f((Mw - nM) * LOG2E);
#pragma unroll
      for (int m = 0; m < 2; ++m)
#pragma unroll
        for (int q = 0; q < 4; ++q) {
          acc_ks[m][q] *= rs;
#pragma unroll
          for (int nf = 0; nf < 4; ++nf) acc2[m][nf][q] *= rs;
        }
      Mw = nM;
      // kp-tilde epilogue -> kpL[r][tok] (own rows rq..rq+31)
#pragma unroll
      for (int m = 0; m < 4; ++m) {
        int tb = m * 16 + hi * 4;
        float mv[4], dg[4];
#pragma unroll
        for (int r = 0; r < 4; ++r) {
          int tk = sc * 64 + tb + r;
          mv[r] = smask[tk];
          dg[r] = sdiag[tk];
        }
#pragma unroll
        for (int nf = 0; nf < 2; ++nf) {
          int rr = rq + nf * 16 + lo;
          float v[4];
#pragma unroll
          for (int r = 0; r < 4; ++r) {
            float x = mv[r] * accT[m][nf][r] - mv[r] * mv[r] * dg[r] - Mw;
            v[r] = __builtin_exp2f(x * LOG2E);
          }
          uint2 pk;
          pk.x = cvtpk(v[0], v[1]);
          pk.y = cvtpk(v[2], v[3]);
          *(uint2*)(kpL + rr * 64 + (tb ^ ((lo & 7) << 3))) = pk;
        }
      }
      // ctx MFMA: D[r][e] += kp~[r][n] * Vt[e][n]; + ksum via ones
#pragma unroll
      for (int kk = 0; kk < 2; ++kk) {
        bf16x8 aC[2], bV[4];
#pragma unroll
        for (int m = 0; m < 2; ++m)
          aC[m] = *(const bf16x8*)(kpL + (rq + m * 16 + lo) * 64 +
                                   ((kk * 32 + hi * 8) ^ ((lo & 7) << 3)));
#pragma unroll
        for (int nf = 0; nf < 4; ++nf)
          bV[nf] = *(const bf16x8*)(VL + (nf * 16 + lo) * 256 +
                                    ((sc * 64 + kk * 32 + hi * 8) ^ ((lo & 7) << 3)));
#pragma unroll
        for (int m = 0; m < 2; ++m) {
          acc_ks[m] = __builtin_amdgcn_mfma_f32_16x16x32_bf16(aC[m], ones, acc_ks[m], 0, 0, 0);
#pragma unroll
          for (int nf = 0; nf < 4; ++nf)
            acc2[m][nf] = __builtin_amdgcn_mfma_f32_16x16x32_bf16(aC[m], bV[nf], acc2[m][nf], 0, 0, 0);
        }
      }
    }
  }
  // write partials: part[(bh*8+ck2)*64 + e][r] f32, plus per-wave max
  long pb = ((long)bh * 8 + ck2) * 64;
#pragma unroll
  for (int m = 0; m < 2; ++m) {
    int r0 = rq + m * 16 + hi * 4;
#pragma unroll
    for (int nf = 0; nf < 4; ++nf) {
      int e = nf * 16 + lo;
      *(f32x4*)&part[(pb + e) * 256 + r0] = acc2[m][nf];
    }
    if (lo == 0)
      *(f32x4*)&part_ks[((long)bh * 8 + ck2) * 256 + r0] = acc_ks[m];
  }
  if (l == 0) part_m[((long)bh * 8 + ck2) * 8 + wq] = Mw;
}

// ---------------- reduce partials -> ctxb [bh][80][256] bf16 ----------------
// Reconstructs global key-max M = max over (chunk, wave) Mw; combines with
// exp(Mw - M); applies RATIO and the +EPSK terms (eps * sum(Vm) for ctx,
// eps * N for ksum).
__global__ __launch_bounds__(256) void ctx_reduce2(
    const float* __restrict__ part, const float* __restrict__ part_ks,
    const float* __restrict__ part_m, const u16* __restrict__ Vt,
    u16* __restrict__ ctxb) {
  __shared__ float red[256];
  int bid = blockIdx.x;
  int bh = bid / 80, j = bid % 80;
  int r = threadIdx.x;
  const float* pm = part_m + (long)bh * 64;
  float M = -3.4e38f;
#pragma unroll
  for (int i = 0; i < 64; ++i) M = fmaxf(M, pm[i]);
  int wv = r >> 5;
  float out = 0.f;
  if (j < 64) {
    float s = 0.f;
#pragma unroll
    for (int c = 0; c < 8; ++c)
      s += __builtin_exp2f((pm[c * 8 + wv] - M) * LOG2E) *
           part[(((long)bh * 8 + c) * 64 + j) * 256 + r];
    // sum of masked V row j (for the eps term)
    float sv = 0.f;
    const u16* vr = Vt + ((long)bh * 64 + j) * 4096 + r * 16;
#pragma unroll
    for (int q = 0; q < 2; ++q) {
      bf16x8 v = *(const bf16x8*)(vr + q * 8);
#pragma unroll
      for (int e = 0; e < 8; ++e) sv += bf2f((u16)v[e]);
    }
    red[r] = sv;
    __syncthreads();
    if (r < 32) {
      float t = 0.f;
#pragma unroll
      for (int i = 0; i < 8; ++i) t += red[r * 8 + i];
      red[r] = t;
    }
    __syncthreads();
    float svt = 0.f;
#pragma unroll
    for (int i = 0; i < 32; ++i) svt += red[i];
    out = RATIO * (s + EPSK * svt);
  } else if (j == 64) {
    float s = 0.f;
#pragma unroll
    for (int c = 0; c < 8; ++c)
      s += __builtin_exp2f((pm[c * 8 + wv] - M) * LOG2E) *
           part_ks[((long)bh * 8 + c) * 256 + r];
    out = RATIO * (s + EPSK * 4096.f);
  }
  ctxb[((long)bh * 80 + j) * 256 + r] = f2bf(out);
}

// =====================================================================
// qattn: per (bh, 128-token block): recompute qp in LDS (dd transposed,
// cross-wave rowmax), then D2[j][tok] = ctxb[j][r]*qp[tok][r]; j=64 row
// is the denominator (in-lane).
// =====================================================================
__global__ __launch_bounds__(256) void qattn(
    const u16* __restrict__ Qg, const u16* __restrict__ Pbf,
    const u16* __restrict__ ctxbg, u16* __restrict__ attn) {
  __shared__ __align__(16) u16 L[69632];  // proj 16384 | ctxb 20480 | Q/qp 32768
  __shared__ float sdiagq[128];
  __shared__ float sredq[4 * 128];
  u16* projL = L;
  u16* CL = L + 16384;
  u16* QL = L + 36864;   // overlaid by qp after the rowmax barrier
  u16* qpL = L + 36864;  // [128 tok][256 r]
  int tid = threadIdx.x, l = tid & 63, wq = tid >> 6;
  int lo = l & 15, hi = l >> 4;
  int bh = blockIdx.x;
  int b = bh >> 4, h = bh & 15;
  long tokb = (long)b * 4096 + (long)blockIdx.y * 128;
  int rq = wq * 64, tq = wq * 32;
  // stage proj (swizzled)
#pragma unroll
  for (int i = 0; i < 8; ++i) {
    int c = wq * 8 + i;
    int row = c * 8 + (l >> 3);
    int sc_ = ((l & 7) * 8) ^ ((row & 7) << 3);
    gl_lds16(Pbf + (long)row * 64 + sc_, projL + c * 512);
  }
  // stage Q tile [128][64] (swizzled)
#pragma unroll
  for (int i = 0; i < 4; ++i) {
    int c = wq * 4 + i;
    int row = c * 8 + (l >> 3);
    int sc_ = ((l & 7) * 8) ^ ((row & 7) << 3);
    gl_lds16(Qg + (tokb + row) * 1024 + (long)h * 64 + sc_, QL + c * 512);
  }
  // stage ctxb tile [80][256] (swizzled)
#pragma unroll
  for (int i = 0; i < 10; ++i) {
    int c = wq * 10 + i;
    int j = 2 * c + (l >> 5);
    int sc_ = ((l & 31) * 8) ^ ((j & 7) << 3);
    gl_lds16(ctxbg + ((long)bh * 80 + j) * 256 + sc_, CL + c * 512);
  }
  asm volatile("s_waitcnt vmcnt(0)" ::: "memory");
  __syncthreads();
  // diag per token (threads 0-127)
  if (tid < 128) {
    float s = 0.f;
#pragma unroll
    for (int j = 0; j < 8; ++j) {
      bf16x8 v = *(const bf16x8*)(QL + tid * 64 + ((j * 8) ^ ((tid & 7) << 3)));
#pragma unroll
      for (int e = 0; e < 8; ++e) {
        float f = bf2f((u16)v[e]);
        s += f * f;
      }
    }
    sdiagq[tid] = s * (1.f / 128.f);
  }
  // dd transposed: D[r][tok], A = proj rows r (wave quadrant), B = Q rows tok
  f32x4 acc[4][8];
#pragma unroll
  for (int m = 0; m < 4; ++m)
#pragma unroll
    for (int nf = 0; nf < 8; ++nf) acc[m][nf] = f32x4{0.f, 0.f, 0.f, 0.f};
#pragma unroll
  for (int kk = 0; kk < 2; ++kk) {
    bf16x8 aP[4], bQ[8];
#pragma unroll
    for (int m = 0; m < 4; ++m)
      aP[m] = *(const bf16x8*)(projL + (rq + m * 16 + lo) * 64 +
                               ((kk * 32 + hi * 8) ^ ((lo & 7) << 3)));
#pragma unroll
    for (int nf = 0; nf < 8; ++nf)
      bQ[nf] = *(const bf16x8*)(QL + (nf * 16 + lo) * 64 +
                                ((kk * 32 + hi * 8) ^ ((lo & 7) << 3)));
#pragma unroll
    for (int m = 0; m < 4; ++m)
#pragma unroll
      for (int nf = 0; nf < 8; ++nf)
        acc[m][nf] = __builtin_amdgcn_mfma_f32_16x16x32_bf16(aP[m], bQ[nf], acc[m][nf], 0, 0, 0);
  }
  // wave-local rowmax per token
#pragma unroll
  for (int nf = 0; nf < 8; ++nf) {
    float vm = acc[0][nf][0];
#pragma unroll
    for (int m = 0; m < 4; ++m)
#pragma unroll
      for (int r = 0; r < 4; ++r) vm = fmaxf(vm, acc[m][nf][r]);
    vm = fmaxf(vm, __shfl_xor(vm, 16, 64));
    vm = fmaxf(vm, __shfl_xor(vm, 32, 64));
    if (hi == 0) sredq[wq * 128 + nf * 16 + lo] = vm;
  }
  __syncthreads();  // also separates QL reads from qp writes
  // final rowmax + epilogue -> qpL[tok][r]
#pragma unroll
  for (int nf = 0; nf < 8; ++nf) {
    int tk = nf * 16 + lo;
    float rm = fmaxf(fmaxf(sredq[tk], sredq[128 + tk]),
                     fmaxf(sredq[256 + tk], sredq[384 + tk]));
    float dg = sdiagq[tk];
#pragma unroll
    for (int m = 0; m < 4; ++m) {
      int r0 = rq + m * 16 + hi * 4;
      float v[4];
#pragma unroll
      for (int r = 0; r < 4; ++r) {
        float x = acc[m][nf][r] - dg - rm;
        v[r] = RATIO * (__builtin_exp2f(x * LOG2E) + EPSK);
      }
      uint2 pk;
      pk.x = cvtpk(v[0], v[1]);
      pk.y = cvtpk(v[2], v[3]);
      *(uint2*)(qpL + tk * 256 + (r0 ^ ((lo & 7) << 3))) = pk;
    }
  }
  __syncthreads();
  // D2[j][tok] = sum_r ctxb[j][r] * qp[tok][r]; wave owns 32 tok
  f32x4 acc2[5][2];
#pragma unroll
  for (int m = 0; m < 5; ++m)
#pragma unroll
    for (int n = 0; n < 2; ++n) acc2[m][n] = f32x4{0.f, 0.f, 0.f, 0.f};
#pragma unroll
  for (int ks = 0; ks < 8; ++ks) {
    bf16x8 aC[5], bQp[2];
#pragma unroll
    for (int m = 0; m < 5; ++m)
      aC[m] = *(const bf16x8*)(CL + (m * 16 + lo) * 256 +
                               ((ks * 32 + hi * 8) ^ ((lo & 7) << 3)));
#pragma unroll
    for (int n = 0; n < 2; ++n)
      bQp[n] = *(const bf16x8*)(qpL + (tq + n * 16 + lo) * 256 +
                                ((ks * 32 + hi * 8) ^ ((lo & 7) << 3)));
#pragma unroll
    for (int m = 0; m < 5; ++m)
#pragma unroll
      for (int n = 0; n < 2; ++n)
        acc2[m][n] = __builtin_amdgcn_mfma_f32_16x16x32_bf16(aC[m], bQp[n], acc2[m][n], 0, 0, 0);
  }
  // epilogue: denom at j=64 (m=4, hi=0, reg=0) -> broadcast via shfl(lane = lo)
#pragma unroll
  for (int n = 0; n < 2; ++n) {
    float dv = __shfl(acc2[4][n][0], lo, 64);
    float di = 1.f / dv;
    long tok = tokb + tq + n * 16 + lo;
#pragma unroll
    for (int m = 0; m < 4; ++m) {
      int j0 = m * 16 + hi * 4;
      uint2 pk;
      pk.x = cvtpk(acc2[m][n][0] * di, acc2[m][n][1] * di);
      pk.y = cvtpk(acc2[m][n][2] * di, acc2[m][n][3] * di);
      *(uint2*)&attn[tok * 1024 + (long)h * 64 + j0] = pk;
    }
  }
}

extern "C" void kernel_launch(void* const* d_in, const int* in_sizes, int n_in,
                              void* d_out, int out_size, void* d_ws, size_t ws_size,
                              hipStream_t stream) {
  const float* X = (const float*)d_in[0];
  const float* mask = (const float*)d_in[1];
  const float* Wq = (const float*)d_in[2];
  const float* bq = (const float*)d_in[3];
  const float* Wk = (const float*)d_in[4];
  const float* bk = (const float*)d_in[5];
  const float* Wv = (const float*)d_in[6];
  const float* bv = (const float*)d_in[7];
  const float* Wff = (const float*)d_in[8];
  const float* bff = (const float*)d_in[9];
  const float* proj = (const float*)d_in[10];
  float* out = (float*)d_out;

  char* p = (char*)d_ws;
  u16* Xbf = (u16*)p;   p += 16777216;   // [8192][1024] bf16; reused as attn
  u16* Wqkv = (u16*)p;  p += 6291456;    // [3072][1024]
  u16* Wffb = (u16*)p;  p += 2097152;    // [1024][1024]
  u16* Pbf = (u16*)p;   p += 32768;      // bf16(proj/8) [256][64]
  u16* Qbf = (u16*)p;   p += 16777216;
  u16* Kbf = (u16*)p;   p += 16777216;
  u16* Vt = (u16*)p;    p += 16777216;   // [bh*64+e][4096] (mask applied)
  u16* ctxb = (u16*)p;  p += 1310720;    // [bh][80][256]
  float* part = (float*)p;    p += 16777216;  // [bh*8][64][256] f32
  float* part_ks = (float*)p; p += 262144;    // [bh*8][256] f32
  float* part_m = (float*)p;  p += 8192;      // [bh*8][8] f32
  u16* attn = Xbf;

  cvt_all<<<12304, 256, 0, stream>>>(X, Wq, Wk, Wv, Wff, proj, Xbf, Wqkv, Wffb, Pbf);
  gemmring<0, 24><<<768, 512, 0, stream>>>(Xbf, Wqkv, bq, bk, bv, mask, Qbf, Kbf, Vt, nullptr, nullptr);
  kctx<<<dim3(32, 8), 512, 0, stream>>>(Kbf, Pbf, Vt, mask, part, part_ks, part_m);
  ctx_reduce2<<<2560, 256, 0, stream>>>(part, part_ks, part_m, Vt, ctxb);
  qattn<<<dim3(32, 32), 256, 0, stream>>>(Qbf, Pbf, ctxb, attn);
  gemmring<1, 8><<<256, 512, 0, stream>>>(attn, Wffb, nullptr, nullptr, nullptr, nullptr,
                                          nullptr, nullptr, nullptr, out, bff);
}

// Round 8
// 158.669 us; speedup vs baseline: 1.1676x; 1.0229x over previous
//
#include <hip/hip_runtime.h>
#include <math.h>

typedef unsigned short u16;
typedef short bf16x8 __attribute__((ext_vector_type(8)));   // 8 bf16 in 4 VGPR
typedef float f32x4 __attribute__((ext_vector_type(4)));
typedef u16 u16x4 __attribute__((ext_vector_type(4)));

#define RATIO 0.0625f   // 256^-0.5
#define EPSK 1e-4f
#define LOG2E 1.44269504f

__device__ __forceinline__ float bf2f(u16 u) {
  return __uint_as_float(((unsigned)u) << 16);
}
__device__ __forceinline__ u16 f2bf(float f) {
  unsigned x = __float_as_uint(f);
  x = x + 0x7fffu + ((x >> 16) & 1u);   // RNE
  return (u16)(x >> 16);
}
__device__ __forceinline__ unsigned cvtpk(float a, float b) {  // [lo=bf16(a), hi=bf16(b)]
  unsigned d;
  asm("v_cvt_pk_bf16_f32 %0, %1, %2" : "=v"(d) : "v"(a), "v"(b));
  return d;
}

using as1v = __attribute__((address_space(1))) void;
using as3v = __attribute__((address_space(3))) void;
__device__ __forceinline__ void gl_lds16(const void* g, void* l) {
  __builtin_amdgcn_global_load_lds((as1v*)g, (as3v*)l, 16, 0, 0);
}

// ---------------- all f32 -> bf16 conversions in one launch ----------------
__global__ __launch_bounds__(256) void cvt_all(
    const float* __restrict__ X, const float* __restrict__ Wq, const float* __restrict__ Wk,
    const float* __restrict__ Wv, const float* __restrict__ Wff, const float* __restrict__ proj,
    u16* __restrict__ Xbf, u16* __restrict__ Wqkv, u16* __restrict__ Wffb, u16* __restrict__ Pbf) {
  long bid = blockIdx.x;
  const float* src;
  u16* dst;
  long off;
  float sc = 1.f;
  if (bid < 8192) { src = X; dst = Xbf; off = bid; }
  else if (bid < 9216) { src = Wq; dst = Wqkv; off = bid - 8192; }
  else if (bid < 10240) { src = Wk; dst = Wqkv + 1048576; off = bid - 9216; }
  else if (bid < 11264) { src = Wv; dst = Wqkv + 2097152; off = bid - 10240; }
  else if (bid < 12288) { src = Wff; dst = Wffb; off = bid - 11264; }
  else { src = proj; dst = Pbf; off = bid - 12288; sc = 0.125f; }
  long i = (off * 256 + threadIdx.x) * 4;
  f32x4 v = *(const f32x4*)(src + i);
  u16x4 o;
#pragma unroll
  for (int j = 0; j < 4; ++j) o[j] = f2bf(v[j] * sc);
  *(u16x4*)(dst + i) = o;
}

// =====================================================================
// Ring GEMM (R5-proven): 256x128 tile, BK=64, 8 waves (4M x 2N), 64x64
// per wave. Ring-of-3 LDS slots (144 KB). ONE barrier + ONE counted
// vmcnt(6) per K-tile; staging runs 2 tiles ahead. Read-side XOR swizzle
// with pre-swizzled global source (0 bank conflicts). EPI 0=qkv, 1=ff.
// =====================================================================
template <int EPI, int NB>
__global__ __launch_bounds__(512, 1) void gemmring(
    const u16* __restrict__ A, const u16* __restrict__ Bw,
    const float* __restrict__ bq, const float* __restrict__ bk,
    const float* __restrict__ bv, const float* __restrict__ mask,
    u16* __restrict__ Q, u16* __restrict__ Kb, u16* __restrict__ Vt,
    float* __restrict__ Of, const float* __restrict__ bff) {
  __shared__ __align__(16) u16 lds[3 * 24576];  // 144 KB: slot = [A 256x64 | B 128x64]
  const int nt = 16;  // K = 1024, BK = 64
  int tid = threadIdx.x;
  int l = tid & 63, w = tid >> 6;
  int wm = w >> 1, wn = w & 1;
  int lo = l & 15, hi = l >> 4;
  int bid = blockIdx.x;
  int swz = (bid & 7) * ((NB * 32) / 8) + (bid >> 3);  // bijective XCD swizzle (grid%8==0)
  long m0 = (long)(swz / NB) * 256;
  long c0 = (long)(swz % NB) * 128;
  int srow = tid >> 3;                              // staging row 0..63
  int sce = ((tid & 7) ^ ((tid >> 3) & 7)) * 8;     // pre-swizzled source col
  f32x4 acc[4][4] = {};

  auto stageA = [&](int t) {
    u16* ub = (u16*)lds + (t % 3) * 24576;
    long k0 = (long)t * 64;
#pragma unroll
    for (int u = 0; u < 2; ++u)
#pragma unroll
      for (int j = 0; j < 2; ++j) {
        long row = m0 + u * 128 + j * 64 + srow;
        gl_lds16(A + row * 1024 + k0 + sce, ub + u * 8192 + j * 4096 + tid * 8);
      }
  };
  auto stageB = [&](int t) {
    u16* ub = (u16*)lds + (t % 3) * 24576 + 16384;
    long k0 = (long)t * 64;
#pragma unroll
    for (int j = 0; j < 2; ++j) {
      long row = c0 + j * 64 + srow;
      gl_lds16(Bw + row * 1024 + k0 + sce, ub + j * 4096 + tid * 8);
    }
  };

  // prologue: tiles 0 and 1 in flight (12 loads/thread)
  stageA(0); stageB(0);
  stageA(1); stageB(1);

  int arb = (wm & 1) * 64;
  for (int t = 0; t < nt; ++t) {
    // wait tile t's 6 loads (leave tile t+1's 6 in flight)
    if (t < nt - 1) {
      asm volatile("s_waitcnt vmcnt(6)" ::: "memory");
    } else {
      asm volatile("s_waitcnt vmcnt(0)" ::: "memory");
    }
    __builtin_amdgcn_s_barrier();
    __builtin_amdgcn_sched_barrier(0);
    const u16* Au = (const u16*)lds + (t % 3) * 24576 + (wm >> 1) * 8192;
    const u16* Bu = (const u16*)lds + (t % 3) * 24576 + 16384;
    bf16x8 areg[4][2], breg[4][2];
#pragma unroll
    for (int mf = 0; mf < 4; ++mf) {
      int lrow = arb + mf * 16 + lo;
#pragma unroll
      for (int kk = 0; kk < 2; ++kk)
        areg[mf][kk] = *(const bf16x8*)(Au + lrow * 64 + ((kk * 32 + hi * 8) ^ ((lo & 7) << 3)));
    }
#pragma unroll
    for (int nf = 0; nf < 4; ++nf) {
      int lrow = wn * 64 + nf * 16 + lo;
#pragma unroll
      for (int kk = 0; kk < 2; ++kk)
        breg[nf][kk] = *(const bf16x8*)(Bu + lrow * 64 + ((kk * 32 + hi * 8) ^ ((lo & 7) << 3)));
    }
    // stage tile t+2 into slot (t+2)%3 == (t-1)%3 (its readers finished
    // before barrier(t) above)
    if (t + 2 < nt) { stageA(t + 2); stageB(t + 2); }
    // MFMA; compiler interleaves with partial lgkmcnt waits
#pragma unroll
    for (int mf = 0; mf < 4; ++mf)
#pragma unroll
      for (int nf = 0; nf < 4; ++nf)
#pragma unroll
        for (int kk = 0; kk < 2; ++kk)
          acc[mf][nf] = __builtin_amdgcn_mfma_f32_16x16x32_bf16(areg[mf][kk], breg[nf][kk],
                                                                acc[mf][nf], 0, 0, 0);
  }

  // ---- epilogue ----
  long rowb = m0 + wm * 64;
  if (EPI == 0) {
    int wsel = (int)(c0 >> 10);  // 0=Q 1=K 2=V
    long cw = c0 & 1023;
    if (wsel < 2) {
      const float* bias = wsel ? bk : bq;
      u16* O = wsel ? Kb : Q;
#pragma unroll
      for (int mf = 0; mf < 4; ++mf)
#pragma unroll
        for (int nf = 0; nf < 4; ++nf) {
          long col = cw + wn * 64 + nf * 16 + lo;
          float bi = bias[col];
#pragma unroll
          for (int r = 0; r < 4; ++r) {
            long row = rowb + mf * 16 + hi * 4 + r;
            O[row * 1024 + col] = f2bf(acc[mf][nf][r] + bi);
          }
        }
    } else {
#pragma unroll
      for (int mf = 0; mf < 4; ++mf) {
        long t4 = rowb + mf * 16 + hi * 4;  // 4 consecutive tokens
        long b = t4 >> 12;
        long nn = t4 & 4095;
#pragma unroll
        for (int nf = 0; nf < 4; ++nf) {
          long col = cw + wn * 64 + nf * 16 + lo;
          float bi = bv[col];
          long h = col >> 6, e = col & 63;
          u16x4 pk;
#pragma unroll
          for (int r = 0; r < 4; ++r) pk[r] = f2bf((acc[mf][nf][r] + bi) * mask[t4 + r]);
          *(u16x4*)&Vt[((b * 16 + h) * 64 + e) * 4096 + nn] = pk;
        }
      }
    }
  } else {
#pragma unroll
    for (int mf = 0; mf < 4; ++mf)
#pragma unroll
      for (int nf = 0; nf < 4; ++nf) {
        long col = c0 + wn * 64 + nf * 16 + lo;
        float bi = bff[col];
#pragma unroll
        for (int r = 0; r < 4; ++r) {
          long row = rowb + mf * 16 + hi * 4 + r;
          Of[row * 1024 + col] = acc[mf][nf][r] + bi;
        }
      }
  }
}

// =====================================================================
// kctx (online-max): per (bh, 512-token block = 2 chunks of 256):
// recompute kp-tilde = exp(mask*dd - mask^2*diag - Mw) in LDS with a
// per-wave RUNNING max Mw (rescaling accumulators by exp(Mw_old-Mw_new));
// accumulate ctx/ksum partials + (wave 0) unscaled vsum[e] = sum_n Vm[n,e]
// via a ones-A MFMA. ctx partials stored bf16; ksum/vsum f32.
// =====================================================================
__global__ __launch_bounds__(512) void kctx(
    const u16* __restrict__ Kg, const u16* __restrict__ Pbf,
    const u16* __restrict__ Vt, const float* __restrict__ mask,
    u16* __restrict__ part, float* __restrict__ part_ks,
    float* __restrict__ part_m, float* __restrict__ part_vs) {
  __shared__ __align__(16) u16 projL[256 * 64];  // 32KB
  __shared__ __align__(16) u16 KL[256 * 64];     // 32KB
  __shared__ __align__(16) u16 VL[64 * 256];     // 32KB
  __shared__ __align__(16) u16 kpL[256 * 64];    // 32KB  [r][tok]
  __shared__ float sdiag[256];
  __shared__ float smask[256];
  int tid = threadIdx.x, l = tid & 63, wq = tid >> 6;
  int lo = l & 15, hi = l >> 4;
  int bh = blockIdx.x, ck2 = blockIdx.y;
  int b = bh >> 4, h = bh & 15;
  int rq = wq * 32;  // wave's 32 r-rows
  int rl = l >> 3;
  // stage proj once (4 chunks of 8 rows per wave)
#pragma unroll
  for (int i = 0; i < 4; ++i) {
    int c = i * 8 + wq;
    int row = c * 8 + rl;
    int sc_ = ((l & 7) * 8) ^ ((row & 7) << 3);
    gl_lds16(Pbf + (long)row * 64 + sc_, projL + c * 512);
  }
  bf16x8 ones;
#pragma unroll
  for (int e = 0; e < 8; ++e) ones[e] = (short)0x3F80;
  float Mw = -3.4e38f;
  f32x4 acc2[2][4] = {};
  f32x4 acc_ks[2] = {};
  f32x4 acc_vs[4] = {};
  for (int s = 0; s < 2; ++s) {
    int ck = ck2 * 2 + s;
    long tg0 = (long)b * 4096 + (long)ck * 256;
    if (s) __syncthreads();  // all reads of previous chunk's KL/VL/sdiag done
    // stage K chunk [256][64]
#pragma unroll
    for (int i = 0; i < 4; ++i) {
      int c = i * 8 + wq;
      int row = c * 8 + rl;
      int sc_ = ((l & 7) * 8) ^ ((row & 7) << 3);
      gl_lds16(Kg + (tg0 + row) * 1024 + (long)h * 64 + sc_, KL + c * 512);
    }
    // stage Vt tile [64 e][256 n]
#pragma unroll
    for (int i = 0; i < 4; ++i) {
      int c = i * 8 + wq;
      int e = 2 * c + (l >> 5);
      int sc_ = ((l & 31) * 8) ^ ((e & 7) << 3);
      gl_lds16(Vt + ((long)bh * 64 + e) * 4096 + (long)ck * 256 + sc_, VL + c * 512);
    }
    asm volatile("s_waitcnt vmcnt(0)" ::: "memory");
    __syncthreads();
    // per-token diag + mask (threads 0-255)
    if (tid < 256) {
      float sm = 0.f;
#pragma unroll
      for (int j = 0; j < 8; ++j) {
        bf16x8 v = *(const bf16x8*)(KL + tid * 64 + ((j * 8) ^ ((tid & 7) << 3)));
#pragma unroll
        for (int e = 0; e < 8; ++e) {
          float f = bf2f((u16)v[e]);
          sm += f * f;
        }
      }
      sdiag[tid] = sm * (1.f / 128.f);
      smask[tid] = mask[tg0 + tid];
    }
    __syncthreads();
    for (int sc = 0; sc < 4; ++sc) {
      // dd: D[tok][r], A = K rows (sc*64..), B = proj rows (rq..rq+31)
      f32x4 accT[4][2] = {};
#pragma unroll
      for (int kk = 0; kk < 2; ++kk) {
        bf16x8 aK[4], bP[2];
#pragma unroll
        for (int m = 0; m < 4; ++m)
          aK[m] = *(const bf16x8*)(KL + (sc * 64 + m * 16 + lo) * 64 +
                                   ((kk * 32 + hi * 8) ^ ((lo & 7) << 3)));
#pragma unroll
        for (int nf = 0; nf < 2; ++nf)
          bP[nf] = *(const bf16x8*)(projL + (rq + nf * 16 + lo) * 64 +
                                    ((kk * 32 + hi * 8) ^ ((lo & 7) << 3)));
#pragma unroll
        for (int m = 0; m < 4; ++m)
#pragma unroll
          for (int nf = 0; nf < 2; ++nf)
            accT[m][nf] = __builtin_amdgcn_mfma_f32_16x16x32_bf16(aK[m], bP[nf], accT[m][nf], 0, 0, 0);
      }
      // online max over mask*dd (wave-wide), rescale accumulators
      float mloc = -3.4e38f;
#pragma unroll
      for (int m = 0; m < 4; ++m) {
        int tb = m * 16 + hi * 4;
#pragma unroll
        for (int r = 0; r < 4; ++r) {
          float mv = smask[sc * 64 + tb + r];
#pragma unroll
          for (int nf = 0; nf < 2; ++nf) mloc = fmaxf(mloc, mv * accT[m][nf][r]);
        }
      }
#pragma unroll
      for (int sft = 1; sft < 64; sft <<= 1) mloc = fmaxf(mloc, __shfl_xor(mloc, sft, 64));
      float nM = fmaxf(Mw, mloc);
      float rs = __builtin_exp2f((Mw - nM) * LOG2E);
#pragma unroll
      for (int m = 0; m < 2; ++m)
#pragma unroll
        for (int q = 0; q < 4; ++q) {
          acc_ks[m][q] *= rs;
#pragma unroll
          for (int nf = 0; nf < 4; ++nf) acc2[m][nf][q] *= rs;
        }
      Mw = nM;
      // kp-tilde epilogue -> kpL[r][tok] (own rows rq..rq+31)
#pragma unroll
      for (int m = 0; m < 4; ++m) {
        int tb = m * 16 + hi * 4;
        float mv[4], dg[4];
#pragma unroll
        for (int r = 0; r < 4; ++r) {
          int tk = sc * 64 + tb + r;
          mv[r] = smask[tk];
          dg[r] = sdiag[tk];
        }
#pragma unroll
        for (int nf = 0; nf < 2; ++nf) {
          int rr = rq + nf * 16 + lo;
          float v[4];
#pragma unroll
          for (int r = 0; r < 4; ++r) {
            float x = mv[r] * accT[m][nf][r] - mv[r] * mv[r] * dg[r] - Mw;
            v[r] = __builtin_exp2f(x * LOG2E);
          }
          uint2 pk;
          pk.x = cvtpk(v[0], v[1]);
          pk.y = cvtpk(v[2], v[3]);
          *(uint2*)(kpL + rr * 64 + (tb ^ ((lo & 7) << 3))) = pk;
        }
      }
      // ctx MFMA: D[r][e] += kp~[r][n] * Vt[e][n]; + ksum via ones;
      // wave 0 also accumulates unscaled vsum[e] = sum_n Vm[n][e]
#pragma unroll
      for (int kk = 0; kk < 2; ++kk) {
        bf16x8 aC[2], bV[4];
#pragma unroll
        for (int m = 0; m < 2; ++m)
          aC[m] = *(const bf16x8*)(kpL + (rq + m * 16 + lo) * 64 +
                                   ((kk * 32 + hi * 8) ^ ((lo & 7) << 3)));
#pragma unroll
        for (int nf = 0; nf < 4; ++nf)
          bV[nf] = *(const bf16x8*)(VL + (nf * 16 + lo) * 256 +
                                    ((sc * 64 + kk * 32 + hi * 8) ^ ((lo & 7) << 3)));
#pragma unroll
        for (int m = 0; m < 2; ++m) {
          acc_ks[m] = __builtin_amdgcn_mfma_f32_16x16x32_bf16(aC[m], ones, acc_ks[m], 0, 0, 0);
#pragma unroll
          for (int nf = 0; nf < 4; ++nf)
            acc2[m][nf] = __builtin_amdgcn_mfma_f32_16x16x32_bf16(aC[m], bV[nf], acc2[m][nf], 0, 0, 0);
        }
        if (wq == 0) {
#pragma unroll
          for (int nf = 0; nf < 4; ++nf)
            acc_vs[nf] = __builtin_amdgcn_mfma_f32_16x16x32_bf16(ones, bV[nf], acc_vs[nf], 0, 0, 0);
        }
      }
    }
  }
  // write partials: part (bf16) [(bh*8+ck2)*64 + e][256 r], ksum f32,
  // per-wave max, wave-0 vsum f32
  long pb = ((long)bh * 8 + ck2) * 64;
#pragma unroll
  for (int m = 0; m < 2; ++m) {
    int r0 = rq + m * 16 + hi * 4;
#pragma unroll
    for (int nf = 0; nf < 4; ++nf) {
      int e = nf * 16 + lo;
      uint2 pk;
      pk.x = cvtpk(acc2[m][nf][0], acc2[m][nf][1]);
      pk.y = cvtpk(acc2[m][nf][2], acc2[m][nf][3]);
      *(uint2*)&part[(pb + e) * 256 + r0] = pk;
    }
    if (lo == 0)
      *(f32x4*)&part_ks[((long)bh * 8 + ck2) * 256 + r0] = acc_ks[m];
  }
  if (l == 0) part_m[((long)bh * 8 + ck2) * 8 + wq] = Mw;
  if (wq == 0 && hi == 0) {
#pragma unroll
    for (int nf = 0; nf < 4; ++nf)
      part_vs[((long)bh * 8 + ck2) * 64 + nf * 16 + lo] = acc_vs[nf][0];
  }
}

// ---------------- reduce partials -> ctxb [bh][80][256] bf16 ----------------
// Reconstructs global key-max M = max over (chunk, wave) Mw; combines with
// exp(Mw - M); applies RATIO and +EPSK terms (eps * vsum for ctx, eps * N
// for ksum). No Vt re-read, no LDS.
__global__ __launch_bounds__(256) void ctx_reduce2(
    const u16* __restrict__ part, const float* __restrict__ part_ks,
    const float* __restrict__ part_m, const float* __restrict__ part_vs,
    u16* __restrict__ ctxb) {
  int bid = blockIdx.x;
  int bh = bid / 80, j = bid % 80;
  int r = threadIdx.x;
  const float* pm = part_m + (long)bh * 64;
  float M = -3.4e38f;
#pragma unroll
  for (int i = 0; i < 64; ++i) M = fmaxf(M, pm[i]);
  int wv = r >> 5;
  float out = 0.f;
  if (j < 64) {
    float s = 0.f, sv = 0.f;
#pragma unroll
    for (int c = 0; c < 8; ++c) {
      s += __builtin_exp2f((pm[c * 8 + wv] - M) * LOG2E) *
           bf2f(part[(((long)bh * 8 + c) * 64 + j) * 256 + r]);
      sv += part_vs[((long)bh * 8 + c) * 64 + j];
    }
    out = RATIO * (s + EPSK * sv);
  } else if (j == 64) {
    float s = 0.f;
#pragma unroll
    for (int c = 0; c < 8; ++c)
      s += __builtin_exp2f((pm[c * 8 + wv] - M) * LOG2E) *
           part_ks[((long)bh * 8 + c) * 256 + r];
    out = RATIO * (s + EPSK * 4096.f);
  }
  ctxb[((long)bh * 80 + j) * 256 + r] = f2bf(out);
}

// =====================================================================
// qattn: per (bh, 128-token block): recompute qp in LDS (dd transposed,
// cross-wave rowmax), then D2[j][tok] = ctxb[j][r]*qp[tok][r]; j=64 row
// is the denominator (in-lane).
// =====================================================================
__global__ __launch_bounds__(256) void qattn(
    const u16* __restrict__ Qg, const u16* __restrict__ Pbf,
    const u16* __restrict__ ctxbg, u16* __restrict__ attn) {
  __shared__ __align__(16) u16 L[69632];  // proj 16384 | ctxb 20480 | Q/qp 32768
  __shared__ float sdiagq[128];
  __shared__ float sredq[4 * 128];
  u16* projL = L;
  u16* CL = L + 16384;
  u16* QL = L + 36864;   // overlaid by qp after the rowmax barrier
  u16* qpL = L + 36864;  // [128 tok][256 r]
  int tid = threadIdx.x, l = tid & 63, wq = tid >> 6;
  int lo = l & 15, hi = l >> 4;
  int bh = blockIdx.x;
  int b = bh >> 4, h = bh & 15;
  long tokb = (long)b * 4096 + (long)blockIdx.y * 128;
  int rq = wq * 64, tq = wq * 32;
  // stage proj (swizzled)
#pragma unroll
  for (int i = 0; i < 8; ++i) {
    int c = wq * 8 + i;
    int row = c * 8 + (l >> 3);
    int sc_ = ((l & 7) * 8) ^ ((row & 7) << 3);
    gl_lds16(Pbf + (long)row * 64 + sc_, projL + c * 512);
  }
  // stage Q tile [128][64] (swizzled)
#pragma unroll
  for (int i = 0; i < 4; ++i) {
    int c = wq * 4 + i;
    int row = c * 8 + (l >> 3);
    int sc_ = ((l & 7) * 8) ^ ((row & 7) << 3);
    gl_lds16(Qg + (tokb + row) * 1024 + (long)h * 64 + sc_, QL + c * 512);
  }
  // stage ctxb tile [80][256] (swizzled)
#pragma unroll
  for (int i = 0; i < 10; ++i) {
    int c = wq * 10 + i;
    int j = 2 * c + (l >> 5);
    int sc_ = ((l & 31) * 8) ^ ((j & 7) << 3);
    gl_lds16(ctxbg + ((long)bh * 80 + j) * 256 + sc_, CL + c * 512);
  }
  asm volatile("s_waitcnt vmcnt(0)" ::: "memory");
  __syncthreads();
  // diag per token (threads 0-127)
  if (tid < 128) {
    float s = 0.f;
#pragma unroll
    for (int j = 0; j < 8; ++j) {
      bf16x8 v = *(const bf16x8*)(QL + tid * 64 + ((j * 8) ^ ((tid & 7) << 3)));
#pragma unroll
      for (int e = 0; e < 8; ++e) {
        float f = bf2f((u16)v[e]);
        s += f * f;
      }
    }
    sdiagq[tid] = s * (1.f / 128.f);
  }
  // dd transposed: D[r][tok], A = proj rows r (wave quadrant), B = Q rows tok
  f32x4 acc[4][8];
#pragma unroll
  for (int m = 0; m < 4; ++m)
#pragma unroll
    for (int nf = 0; nf < 8; ++nf) acc[m][nf] = f32x4{0.f, 0.f, 0.f, 0.f};
#pragma unroll
  for (int kk = 0; kk < 2; ++kk) {
    bf16x8 aP[4], bQ[8];
#pragma unroll
    for (int m = 0; m < 4; ++m)
      aP[m] = *(const bf16x8*)(projL + (rq + m * 16 + lo) * 64 +
                               ((kk * 32 + hi * 8) ^ ((lo & 7) << 3)));
#pragma unroll
    for (int nf = 0; nf < 8; ++nf)
      bQ[nf] = *(const bf16x8*)(QL + (nf * 16 + lo) * 64 +
                                ((kk * 32 + hi * 8) ^ ((lo & 7) << 3)));
#pragma unroll
    for (int m = 0; m < 4; ++m)
#pragma unroll
      for (int nf = 0; nf < 8; ++nf)
        acc[m][nf] = __builtin_amdgcn_mfma_f32_16x16x32_bf16(aP[m], bQ[nf], acc[m][nf], 0, 0, 0);
  }
  // wave-local rowmax per token
#pragma unroll
  for (int nf = 0; nf < 8; ++nf) {
    float vm = acc[0][nf][0];
#pragma unroll
    for (int m = 0; m < 4; ++m)
#pragma unroll
      for (int r = 0; r < 4; ++r) vm = fmaxf(vm, acc[m][nf][r]);
    vm = fmaxf(vm, __shfl_xor(vm, 16, 64));
    vm = fmaxf(vm, __shfl_xor(vm, 32, 64));
    if (hi == 0) sredq[wq * 128 + nf * 16 + lo] = vm;
  }
  __syncthreads();  // also separates QL reads from qp writes
  // final rowmax + epilogue -> qpL[tok][r]
#pragma unroll
  for (int nf = 0; nf < 8; ++nf) {
    int tk = nf * 16 + lo;
    float rm = fmaxf(fmaxf(sredq[tk], sredq[128 + tk]),
                     fmaxf(sredq[256 + tk], sredq[384 + tk]));
    float dg = sdiagq[tk];
#pragma unroll
    for (int m = 0; m < 4; ++m) {
      int r0 = rq + m * 16 + hi * 4;
      float v[4];
#pragma unroll
      for (int r = 0; r < 4; ++r) {
        float x = acc[m][nf][r] - dg - rm;
        v[r] = RATIO * (__builtin_exp2f(x * LOG2E) + EPSK);
      }
      uint2 pk;
      pk.x = cvtpk(v[0], v[1]);
      pk.y = cvtpk(v[2], v[3]);
      *(uint2*)(qpL + tk * 256 + (r0 ^ ((lo & 7) << 3))) = pk;
    }
  }
  __syncthreads();
  // D2[j][tok] = sum_r ctxb[j][r] * qp[tok][r]; wave owns 32 tok
  f32x4 acc2[5][2];
#pragma unroll
  for (int m = 0; m < 5; ++m)
#pragma unroll
    for (int n = 0; n < 2; ++n) acc2[m][n] = f32x4{0.f, 0.f, 0.f, 0.f};
#pragma unroll
  for (int ks = 0; ks < 8; ++ks) {
    bf16x8 aC[5], bQp[2];
#pragma unroll
    for (int m = 0; m < 5; ++m)
      aC[m] = *(const bf16x8*)(CL + (m * 16 + lo) * 256 +
                               ((ks * 32 + hi * 8) ^ ((lo & 7) << 3)));
#pragma unroll
    for (int n = 0; n < 2; ++n)
      bQp[n] = *(const bf16x8*)(qpL + (tq + n * 16 + lo) * 256 +
                                ((ks * 32 + hi * 8) ^ ((lo & 7) << 3)));
#pragma unroll
    for (int m = 0; m < 5; ++m)
#pragma unroll
      for (int n = 0; n < 2; ++n)
        acc2[m][n] = __builtin_amdgcn_mfma_f32_16x16x32_bf16(aC[m], bQp[n], acc2[m][n], 0, 0, 0);
  }
  // epilogue: denom at j=64 (m=4, hi=0, reg=0) -> broadcast via shfl(lane = lo)
#pragma unroll
  for (int n = 0; n < 2; ++n) {
    float dv = __shfl(acc2[4][n][0], lo, 64);
    float di = 1.f / dv;
    long tok = tokb + tq + n * 16 + lo;
#pragma unroll
    for (int m = 0; m < 4; ++m) {
      int j0 = m * 16 + hi * 4;
      uint2 pk;
      pk.x = cvtpk(acc2[m][n][0] * di, acc2[m][n][1] * di);
      pk.y = cvtpk(acc2[m][n][2] * di, acc2[m][n][3] * di);
      *(uint2*)&attn[tok * 1024 + (long)h * 64 + j0] = pk;
    }
  }
}

extern "C" void kernel_launch(void* const* d_in, const int* in_sizes, int n_in,
                              void* d_out, int out_size, void* d_ws, size_t ws_size,
                              hipStream_t stream) {
  const float* X = (const float*)d_in[0];
  const float* mask = (const float*)d_in[1];
  const float* Wq = (const float*)d_in[2];
  const float* bq = (const float*)d_in[3];
  const float* Wk = (const float*)d_in[4];
  const float* bk = (const float*)d_in[5];
  const float* Wv = (const float*)d_in[6];
  const float* bv = (const float*)d_in[7];
  const float* Wff = (const float*)d_in[8];
  const float* bff = (const float*)d_in[9];
  const float* proj = (const float*)d_in[10];
  float* out = (float*)d_out;

  char* p = (char*)d_ws;
  u16* Xbf = (u16*)p;   p += 16777216;   // [8192][1024] bf16; reused as attn
  u16* Wqkv = (u16*)p;  p += 6291456;    // [3072][1024]
  u16* Wffb = (u16*)p;  p += 2097152;    // [1024][1024]
  u16* Pbf = (u16*)p;   p += 32768;      // bf16(proj/8) [256][64]
  u16* Qbf = (u16*)p;   p += 16777216;
  u16* Kbf = (u16*)p;   p += 16777216;
  u16* Vt = (u16*)p;    p += 16777216;   // [bh*64+e][4096] (mask applied)
  u16* ctxb = (u16*)p;  p += 1310720;    // [bh][80][256]
  u16* part = (u16*)p;      p += 8388608;  // [bh*8][64][256] bf16
  float* part_ks = (float*)p; p += 262144; // [bh*8][256] f32
  float* part_m = (float*)p;  p += 8192;   // [bh*8][8] f32
  float* part_vs = (float*)p; p += 65536;  // [bh*8][64] f32
  u16* attn = Xbf;

  cvt_all<<<12304, 256, 0, stream>>>(X, Wq, Wk, Wv, Wff, proj, Xbf, Wqkv, Wffb, Pbf);
  gemmring<0, 24><<<768, 512, 0, stream>>>(Xbf, Wqkv, bq, bk, bv, mask, Qbf, Kbf, Vt, nullptr, nullptr);
  kctx<<<dim3(32, 8), 512, 0, stream>>>(Kbf, Pbf, Vt, mask, part, part_ks, part_m, part_vs);
  ctx_reduce2<<<2560, 256, 0, stream>>>(part, part_ks, part_m, part_vs, ctxb);
  qattn<<<dim3(32, 32), 256, 0, stream>>>(Qbf, Pbf, ctxb, attn);
  gemmring<1, 8><<<256, 512, 0, stream>>>(attn, Wffb, nullptr, nullptr, nullptr, nullptr,
                                          nullptr, nullptr, nullptr, out, bff);
}